// Round 4
// baseline (197.153 us; speedup 1.0000x reference)
//
#include <hip/hip_runtime.h>

// LengthRegulator: B=32, P=1024, D=384, T=max_length=3072 (fixed shapes).
// One fused kernel. Each block: re-scan its batch's 1024 durations (4 KB,
// L2-hot, shfl scan), build t->src-row map for its 192-row T-chunk via O(dur)
// LDS scatter, then coalesced float4 row-gather with nontemporal stores
// (output is write-once; keep x hot in L2). 1-D grid with XCD swizzle so all
// 16 chunks of a batch share the same blockIdx%8 (same-XCD heuristic).
// Output 1 (lengths) stored as float32 in the tail of d_out.

#define BB 32
#define PP 1024
#define DD 384
#define TT 3072
#define NCHUNK 16
#define CHUNK (TT / NCHUNK)      // 192 output rows per block
#define BLOCK 512                // 8 waves
#define NWAVE (BLOCK / 64)
#define ROW4 (DD / 4)            // 96 float4 per row
#define ITERS (CHUNK * ROW4 / BLOCK)  // 36, exact

// native clang vector — required by __builtin_nontemporal_store
typedef float f4 __attribute__((ext_vector_type(4)));

__global__ __launch_bounds__(BLOCK) void lr_fused_kernel(
    const float* __restrict__ x, const int* __restrict__ dur,
    float* __restrict__ out, float* __restrict__ len_out)
{
    __shared__ int lidx[CHUNK];
    __shared__ int wtot[NWAVE];

    const int tid  = threadIdx.x;
    const int lane = tid & 63;
    const int wv   = tid >> 6;

    // XCD swizzle: all 16 chunks of a batch share gid%8 -> same XCD residue.
    const int gid = blockIdx.x;
    const int b   = (gid & 7) + ((gid >> 7) << 3);   // 0..31
    const int ck  = (gid >> 3) & 15;                 // 0..15
    const int lo  = ck * CHUNK;

    // ---- block-wide inclusive scan of durations (2 elems/thread, int2) ----
    int2 d = ((const int2*)(dur + b * PP))[tid];
    const int s = d.x + d.y;
    int wsum = s;
    #pragma unroll
    for (int off = 1; off < 64; off <<= 1) {
        int v = __shfl_up(wsum, off, 64);
        if (lane >= off) wsum += v;
    }
    if (lane == 63) wtot[wv] = wsum;
    for (int i = tid; i < CHUNK; i += BLOCK) lidx[i] = -1;
    __syncthreads();

    int woff = 0, total = 0;
    #pragma unroll
    for (int w = 0; w < NWAVE; ++w) {
        int v = wtot[w];
        if (w < wv) woff += v;
        total += v;
    }
    const int pre    = woff + wsum - s;            // csum before elem 2*tid
    const int outlen = total < TT ? total : TT;

    if (ck == 0 && tid == 0) len_out[b] = (float)outlen;

    // ---- scatter: elem p covers t in [csum[p-1], csum[p]) ----
    {
        const int hi = lo + CHUNK;
        int a0 = pre, a1 = pre + d.x, a2 = pre + s;
        int t0 = a0 > lo ? a0 : lo, e0 = a1 < hi ? a1 : hi;
        for (int t = t0; t < e0; ++t) lidx[t - lo] = 2 * tid;
        int t1 = a1 > lo ? a1 : lo, e1 = a2 < hi ? a2 : hi;
        for (int t = t1; t < e1; ++t) lidx[t - lo] = 2 * tid + 1;
    }
    __syncthreads();

    // ---- gather: 192 rows x 96 float4, block-strided, coalesced ----
    const f4* __restrict__ x4 = (const f4*)(x + (size_t)b * PP * DD);
    f4* __restrict__ o4 = (f4*)(out + ((size_t)b * TT + lo) * DD);

    int t1 = tid / ROW4;            // 0..5
    int c  = tid - t1 * ROW4;       // 0..95
    #pragma unroll 6
    for (int it = 0; it < ITERS; ++it) {
        const int m = lidx[t1];     // LDS broadcast (96 threads/row)
        f4 v = x4[(m < 0 ? 0 : m) * ROW4 + c];
        if (lo + t1 >= outlen) v = (f4)(0.f);
        __builtin_nontemporal_store(v, &o4[t1 * ROW4 + c]);
        // advance e by BLOCK=512 = 5*96 + 32 without a divide
        t1 += 5; c += 32;
        if (c >= ROW4) { c -= ROW4; t1 += 1; }
    }
}

extern "C" void kernel_launch(void* const* d_in, const int* in_sizes, int n_in,
                              void* d_out, int out_size, void* d_ws, size_t ws_size,
                              hipStream_t stream) {
    const float* x   = (const float*)d_in[0];
    const int*   dur = (const int*)d_in[1];
    // d_in[2] = max_length (device scalar) — value 3072, baked into TT.

    float* out     = (float*)d_out;
    float* len_out = out + (size_t)BB * TT * DD;   // 32 lengths in the tail

    lr_fused_kernel<<<NCHUNK * BB, BLOCK, 0, stream>>>(x, dur, out, len_out);
}

// Round 5
// 190.995 us; speedup vs baseline: 1.0322x; 1.0322x over previous
//
#include <hip/hip_runtime.h>

// LengthRegulator: B=32, P=1024, D=384, T=max_length=3072 (fixed shapes).
// Fused single kernel (best-measured variant, R2: 191.6 us): each block
// re-scans its batch's durations (4 KB, L2-hot), builds the t->p index map
// for its T-chunk via O(dur) scatter (replaces dependent-latency LDS binary
// search), then does the coalesced float4 row-gather.
// Second output: output_lengths as float32 in d_out tail.
//
// Note (R4 post-mortem): nt-stores + XCD swizzle measured +5.6us but the
// session's HBM ran ~5% slower (harness fills 89->93us); normalized they are
// neutral. Reverting to the best-measured source; remaining controllable
// delta (<9us vs the 201MB/6.5TB/s = ~31us kernel floor) is below session
// noise — the timed window is ~78% harness poison/restore fills.

#define BB 32
#define PP 1024
#define DD 384
#define TT 3072
#define NCHUNK 16
#define CHUNK (TT / NCHUNK)      // 192 output rows per block
#define BLOCK 512                // 8 waves
#define NWAVE (BLOCK / 64)
#define ROW4 (DD / 4)            // 96 float4 per row

__global__ __launch_bounds__(BLOCK) void lr_fused_kernel(
    const float* __restrict__ x, const int* __restrict__ dur,
    float* __restrict__ out, float* __restrict__ len_out)
{
    __shared__ int lidx[CHUNK];
    __shared__ int wtot[NWAVE];

    const int tid  = threadIdx.x;
    const int lane = tid & 63;
    const int wv   = tid >> 6;
    const int b    = blockIdx.y;
    const int lo   = blockIdx.x * CHUNK;

    // ---- block-wide inclusive scan of durations (2 elems/thread, int2) ----
    int2 d = ((const int2*)(dur + b * PP))[tid];
    const int s = d.x + d.y;
    int wsum = s;
    #pragma unroll
    for (int off = 1; off < 64; off <<= 1) {
        int v = __shfl_up(wsum, off, 64);
        if (lane >= off) wsum += v;
    }
    if (lane == 63) wtot[wv] = wsum;
    // init index map while the scan result lands
    for (int i = tid; i < CHUNK; i += BLOCK) lidx[i] = -1;
    __syncthreads();

    int woff = 0, total = 0;
    #pragma unroll
    for (int w = 0; w < NWAVE; ++w) {
        int v = wtot[w];
        if (w < wv) woff += v;
        total += v;
    }
    const int pre    = woff + wsum - s;            // csum before elem 2*tid
    const int outlen = total < TT ? total : TT;

    if (blockIdx.x == 0 && tid == 0) len_out[b] = (float)outlen;

    // ---- scatter: elem p covers t in [csum[p-1], csum[p]) ----
    {
        const int hi = lo + CHUNK;
        int a0 = pre, a1 = pre + d.x, a2 = pre + s;
        int t0 = a0 > lo ? a0 : lo, e0 = a1 < hi ? a1 : hi;
        for (int t = t0; t < e0; ++t) lidx[t - lo] = 2 * tid;
        int t1 = a1 > lo ? a1 : lo, e1 = a2 < hi ? a2 : hi;
        for (int t = t1; t < e1; ++t) lidx[t - lo] = 2 * tid + 1;
    }
    __syncthreads();

    // ---- gather: CHUNK*96 float4 elements, block-strided, coalesced ----
    const float4* __restrict__ x4 = (const float4*)(x + (size_t)b * PP * DD);
    float4* __restrict__ o4 = (float4*)(out + ((size_t)b * TT + lo) * DD);
    #pragma unroll 4
    for (int e = tid; e < CHUNK * ROW4; e += BLOCK) {
        const int t1 = e / ROW4;
        const int c  = e - t1 * ROW4;
        int m = lidx[t1];                 // LDS broadcast (96 threads/row)
        // always issue the load (clamped) so loads batch; select zero after
        float4 v = x4[(m < 0 ? 0 : m) * ROW4 + c];
        if (lo + t1 >= outlen) v = make_float4(0.f, 0.f, 0.f, 0.f);
        o4[e] = v;
    }
}

extern "C" void kernel_launch(void* const* d_in, const int* in_sizes, int n_in,
                              void* d_out, int out_size, void* d_ws, size_t ws_size,
                              hipStream_t stream) {
    const float* x   = (const float*)d_in[0];
    const int*   dur = (const int*)d_in[1];
    // d_in[2] = max_length (device scalar) — value 3072, baked into TT.

    float* out     = (float*)d_out;
    float* len_out = out + (size_t)BB * TT * DD;   // 32 lengths in the tail

    lr_fused_kernel<<<dim3(NCHUNK, BB), BLOCK, 0, stream>>>(x, dur, out, len_out);
}